// Round 1
// baseline (2085.955 us; speedup 1.0000x reference)
//
#include <hip/hip_runtime.h>

#define DD 512
#define KK 4096
#define NN 32768

// ---------------- 0.5*|e_k|^2 ----------------
__global__ __launch_bounds__(256) void he2_kernel(const float* __restrict__ E,
                                                  float* __restrict__ he2) {
  int k = blockIdx.x * 256 + threadIdx.x;  // 4096 threads, coalesced over k
  float s = 0.f;
#pragma unroll 8
  for (int d = 0; d < DD; ++d) {
    float v = E[(size_t)d * KK + k];
    s = fmaf(v, v, s);
  }
  he2[k] = 0.5f * s;
}

// ---------------- E[D,K] -> Et[K,D] for coalesced gather ----------------
__global__ __launch_bounds__(256) void transpose_kernel(const float* __restrict__ E,
                                                        float* __restrict__ Et) {
  int gid = blockIdx.x * 256 + threadIdx.x;  // D*K total, k fastest => coalesced read
  int d = gid >> 12;
  int k = gid & (KK - 1);
  Et[(size_t)k * DD + d] = E[gid];
}

// ---------------- fused scores + argmax ----------------
// block: 256 threads; BM=64 tokens x all K codes (looped in BK=128 tiles)
// per-thread register tile: 4 tokens x 8 codes, D staged in BD=32 slices via LDS
#define BM 64
#define BK 128
#define BD 32

__global__ __launch_bounds__(256) void argmax_kernel(
    const float* __restrict__ x, const float* __restrict__ E,
    const float* __restrict__ he2, int* __restrict__ idx_out,
    int* __restrict__ counts) {
  __shared__ __align__(16) float xs[BD][68];   // [d][token], pad 68 (16B-aligned rows)
  __shared__ __align__(16) float es[BD][132];  // [d][k], pad 132
  __shared__ float rv[BM][16];
  __shared__ int ri[BM][16];

  const int tid = threadIdx.x;
  const int tm = tid >> 4;  // 0..15 -> tokens tm*4 .. tm*4+3
  const int tk = tid & 15;  // 0..15 -> codes tk*8 .. tk*8+7 within k-tile
  const int block_m = blockIdx.x * BM;

  float best[4];
  int bidx[4];
#pragma unroll
  for (int i = 0; i < 4; ++i) { best[i] = -INFINITY; bidx[i] = 0; }

  for (int kt = 0; kt < KK; kt += BK) {
    float acc[4][8];
#pragma unroll
    for (int i = 0; i < 4; ++i)
#pragma unroll
      for (int j = 0; j < 8; ++j) acc[i][j] = 0.f;

    for (int dt = 0; dt < DD; dt += BD) {
      __syncthreads();
      // stage x tile: 64 tokens x 32 d (transposed into [d][tok])
#pragma unroll
      for (int r = 0; r < 2; ++r) {
        int q = tid + r * 256;  // 0..511
        int tok = q >> 3;       // 0..63
        int d4 = q & 7;         // 0..7
        float4 v = *(const float4*)(x + (size_t)(block_m + tok) * DD + dt + d4 * 4);
        xs[d4 * 4 + 0][tok] = v.x;
        xs[d4 * 4 + 1][tok] = v.y;
        xs[d4 * 4 + 2][tok] = v.z;
        xs[d4 * 4 + 3][tok] = v.w;
      }
      // stage E tile: 32 d x 128 k
#pragma unroll
      for (int r = 0; r < 4; ++r) {
        int q = tid + r * 256;  // 0..1023
        int drow = q >> 5;      // 0..31
        int k4 = q & 31;        // 0..31
        float4 v = *(const float4*)(E + (size_t)(dt + drow) * KK + kt + k4 * 4);
        *(float4*)&es[drow][k4 * 4] = v;
      }
      __syncthreads();
#pragma unroll 8
      for (int d = 0; d < BD; ++d) {
        const float4 a = *(const float4*)&xs[d][tm * 4];
        const float4 b0 = *(const float4*)&es[d][tk * 8];
        const float4 b1 = *(const float4*)&es[d][tk * 8 + 4];
        const float av[4] = {a.x, a.y, a.z, a.w};
        const float bv[8] = {b0.x, b0.y, b0.z, b0.w, b1.x, b1.y, b1.z, b1.w};
#pragma unroll
        for (int i = 0; i < 4; ++i)
#pragma unroll
          for (int j = 0; j < 8; ++j) acc[i][j] = fmaf(av[i], bv[j], acc[i][j]);
      }
    }
    // fold this k-tile into the running best (score = dot - 0.5|e|^2;
    // strict > keeps the earliest index on ties, matching argmin semantics)
    float4 h0 = *(const float4*)(he2 + kt + tk * 8);
    float4 h1 = *(const float4*)(he2 + kt + tk * 8 + 4);
    const float hv[8] = {h0.x, h0.y, h0.z, h0.w, h1.x, h1.y, h1.z, h1.w};
#pragma unroll
    for (int i = 0; i < 4; ++i) {
#pragma unroll
      for (int j = 0; j < 8; ++j) {
        float s = acc[i][j] - hv[j];
        if (s > best[i]) { best[i] = s; bidx[i] = kt + tk * 8 + j; }
      }
    }
  }

  __syncthreads();
#pragma unroll
  for (int i = 0; i < 4; ++i) {
    rv[tm * 4 + i][tk] = best[i];
    ri[tm * 4 + i][tk] = bidx[i];
  }
  __syncthreads();
  if (tid < BM) {
    float bv = rv[tid][0];
    int bi = ri[tid][0];
#pragma unroll
    for (int t = 1; t < 16; ++t) {
      float v = rv[tid][t];
      int ii = ri[tid][t];
      if (v > bv || (v == bv && ii < bi)) { bv = v; bi = ii; }
    }
    idx_out[block_m + tid] = bi;
    atomicAdd(&counts[bi], 1);
  }
}

// ---------------- gather quantized + accumulate sum((q-x)^2) ----------------
__global__ __launch_bounds__(256) void gather_et_kernel(
    const float* __restrict__ x, const float* __restrict__ Et,
    const int* __restrict__ idx, float* __restrict__ out,
    float* __restrict__ partials) {
  __shared__ float sh[256];
  int tid = threadIdx.x;
  int gid = blockIdx.x * 256 + tid;
  int n = gid >> 7;    // D/4 = 128 float4 per token
  int d4 = gid & 127;
  int k = idx[n];
  float4 q = *(const float4*)(Et + (size_t)k * DD + d4 * 4);
  float4 xv = *(const float4*)(x + (size_t)n * DD + d4 * 4);
  *(float4*)(out + (size_t)n * DD + d4 * 4) = q;
  float dx0 = q.x - xv.x, dx1 = q.y - xv.y, dx2 = q.z - xv.z, dx3 = q.w - xv.w;
  sh[tid] = dx0 * dx0 + dx1 * dx1 + dx2 * dx2 + dx3 * dx3;
  __syncthreads();
  for (int s = 128; s > 0; s >>= 1) {
    if (tid < s) sh[tid] += sh[tid + s];
    __syncthreads();
  }
  if (tid == 0) atomicAdd(&partials[blockIdx.x & 255], sh[0]);
}

__global__ __launch_bounds__(256) void gather_direct_kernel(
    const float* __restrict__ x, const float* __restrict__ E,
    const int* __restrict__ idx, float* __restrict__ out,
    float* __restrict__ partials) {
  __shared__ float sh[256];
  int tid = threadIdx.x;
  int gid = blockIdx.x * 256 + tid;
  int n = gid >> 7;
  int d4 = gid & 127;
  int k = idx[n];
  float4 q;
  q.x = E[(size_t)(d4 * 4 + 0) * KK + k];
  q.y = E[(size_t)(d4 * 4 + 1) * KK + k];
  q.z = E[(size_t)(d4 * 4 + 2) * KK + k];
  q.w = E[(size_t)(d4 * 4 + 3) * KK + k];
  float4 xv = *(const float4*)(x + (size_t)n * DD + d4 * 4);
  *(float4*)(out + (size_t)n * DD + d4 * 4) = q;
  float dx0 = q.x - xv.x, dx1 = q.y - xv.y, dx2 = q.z - xv.z, dx3 = q.w - xv.w;
  sh[tid] = dx0 * dx0 + dx1 * dx1 + dx2 * dx2 + dx3 * dx3;
  __syncthreads();
  for (int s = 128; s > 0; s >>= 1) {
    if (tid < s) sh[tid] += sh[tid + s];
    __syncthreads();
  }
  if (tid == 0) atomicAdd(&partials[blockIdx.x & 255], sh[0]);
}

// ---------------- loss + perplexity ----------------
__global__ __launch_bounds__(256) void finalize_kernel(
    const int* __restrict__ counts, const float* __restrict__ partials,
    float* __restrict__ out) {
  __shared__ float sh[256];
  int tid = threadIdx.x;
  float h = 0.f;
  for (int k = tid; k < KK; k += 256) {
    float p = (float)counts[k] * (1.0f / (float)NN);
    h += p * logf(p + 1e-10f);
  }
  sh[tid] = h;
  __syncthreads();
  for (int s = 128; s > 0; s >>= 1) {
    if (tid < s) sh[tid] += sh[tid + s];
    __syncthreads();
  }
  float H = sh[0];
  __syncthreads();
  sh[tid] = partials[tid];
  __syncthreads();
  for (int s = 128; s > 0; s >>= 1) {
    if (tid < s) sh[tid] += sh[tid + s];
    __syncthreads();
  }
  if (tid == 0) {
    float mse = sh[0] / (float)((size_t)NN * DD);
    out[(size_t)NN * DD] = 1.25f * mse;      // q_loss + 0.25*e_loss, equal values
    out[(size_t)NN * DD + 1] = expf(-H);     // perplexity
  }
}

extern "C" void kernel_launch(void* const* d_in, const int* in_sizes, int n_in,
                              void* d_out, int out_size, void* d_ws, size_t ws_size,
                              hipStream_t stream) {
  const float* x = (const float*)d_in[0];
  const float* E = (const float*)d_in[1];
  float* out = (float*)d_out;
  char* ws = (char*)d_ws;

  // ws layout (bytes)
  float* he2 = (float*)(ws + 0);              // 16384
  int* idx = (int*)(ws + 16384);              // 131072
  int* counts = (int*)(ws + 147456);          // 16384
  float* partials = (float*)(ws + 163840);    // 1024
  float* Et = (float*)(ws + 164864);          // 8 MB (optional)
  const size_t need_et = 164864 + (size_t)DD * KK * 4;
  const bool use_et = ws_size >= need_et;

  // zero counts + partials (re-poisoned to 0xAA before every call)
  hipMemsetAsync(ws + 147456, 0, 16384 + 1024, stream);

  he2_kernel<<<KK / 256, 256, 0, stream>>>(E, he2);
  if (use_et) transpose_kernel<<<(DD * KK) / 256, 256, 0, stream>>>(E, Et);
  argmax_kernel<<<NN / BM, 256, 0, stream>>>(x, E, he2, idx, counts);
  if (use_et)
    gather_et_kernel<<<(NN * (DD / 4)) / 256, 256, 0, stream>>>(x, Et, idx, out, partials);
  else
    gather_direct_kernel<<<(NN * (DD / 4)) / 256, 256, 0, stream>>>(x, E, idx, out, partials);
  finalize_kernel<<<1, 256, 0, stream>>>(counts, partials, out);
}

// Round 2
// 2005.343 us; speedup vs baseline: 1.0402x; 1.0402x over previous
//
#include <hip/hip_runtime.h>
#include <stdint.h>

#define DD 512
#define KK 4096
#define NN 32768

#define BM 128       // tokens per block
#define BK 128       // codes per k-tile
#define KS 4         // K-split factor
#define KPB (KK/KS)  // codes per block
#define BD 32        // d-slice per stage

// ---------------- 0.5*|e_k|^2 ----------------
__global__ __launch_bounds__(256) void he2_kernel(const float* __restrict__ E,
                                                  float* __restrict__ he2) {
  int k = blockIdx.x * 256 + threadIdx.x;
  float s = 0.f;
#pragma unroll 8
  for (int d = 0; d < DD; ++d) {
    float v = E[(size_t)d * KK + k];
    s = fmaf(v, v, s);
  }
  he2[k] = 0.5f * s;
}

// ---------------- tiled transpose E[D,K] -> Et[K,D] ----------------
__global__ __launch_bounds__(256) void transpose_kernel(const float* __restrict__ E,
                                                        float* __restrict__ Et) {
  __shared__ float t[32][33];
  int bk = (blockIdx.x & 127) * 32;   // k tile
  int bd = (blockIdx.x >> 7) * 32;    // d tile
  int c = threadIdx.x & 31;
  int r0 = threadIdx.x >> 5;  // 0..7
#pragma unroll
  for (int r = r0; r < 32; r += 8)
    t[r][c] = E[(size_t)(bd + r) * KK + bk + c];
  __syncthreads();
#pragma unroll
  for (int r = r0; r < 32; r += 8)
    Et[(size_t)(bk + r) * DD + bd + c] = t[c][r];
}

// ---------------- fused scores + argmax ----------------
// block: 256 thr = 4 waves (2m x 2k); wave = 8m x 8k lanes; thread: 8 tok x 8 codes
// block tile: 128 tokens x 128 codes per kt, K-split 4 across blocks.
__global__ __launch_bounds__(256, 4) void argmax_kernel(
    const float* __restrict__ x, const float* __restrict__ E,
    const float* __restrict__ he2, unsigned long long* __restrict__ best64) {
  __shared__ __align__(16) char smem[33280];
  float (*xs)[132] = (float (*)[132])smem;            // [BD][BM+4]  16896 B
  float (*es)[BK] = (float (*)[BK])(smem + 16896);    // [BD][BK]    16384 B

  const int tid = threadIdx.x;
  const int wave = tid >> 6;
  const int lane = tid & 63;
  const int wm = wave >> 1, wk = wave & 1;
  const int tm = lane >> 3, tk = lane & 7;
  const int block_m = (blockIdx.x >> 2) * BM;
  const int kbase = (blockIdx.x & 3) * KPB;

  float best[8];
  int bidx[8];
#pragma unroll
  for (int i = 0; i < 8; ++i) { best[i] = -INFINITY; bidx[i] = 0; }

  // staging maps
  const int xtok = tid >> 3;              // 0..31 (+32 per r)
  const int xd4 = tid & 7;                // 0..7
  const int erow_lane = (lane >> 5);      // 0 or 1
  const int ecol = (lane & 31) * 4;

  for (int kt = 0; kt < KPB; kt += BK) {
    const int k0 = kbase + kt;
    float acc[8][8];
#pragma unroll
    for (int i = 0; i < 8; ++i)
#pragma unroll
      for (int j = 0; j < 8; ++j) acc[i][j] = 0.f;

    for (int dt = 0; dt < DD; dt += BD) {
      __syncthreads();
      // E tile: 32 rows x 128 floats, DMA direct to LDS (wave-uniform base + lane*16)
#pragma unroll
      for (int r = 0; r < 4; ++r) {
        int row = r * 8 + wave * 2;  // + erow_lane inside the wave
        const float* gp = E + (size_t)(dt + row + erow_lane) * KK + k0 + ecol;
        __builtin_amdgcn_global_load_lds(
            (const __attribute__((address_space(1))) void*)gp,
            (__attribute__((address_space(3))) void*)&es[row][0], 16, 0, 0);
      }
      // x tile: 128 tok x 32 d, transposed into [d][tok]
#pragma unroll
      for (int r = 0; r < 4; ++r) {
        int tok = xtok + r * 32;
        float4 v = *(const float4*)(x + (size_t)(block_m + tok) * DD + dt + xd4 * 4);
        xs[xd4 * 4 + 0][tok] = v.x;
        xs[xd4 * 4 + 1][tok] = v.y;
        xs[xd4 * 4 + 2][tok] = v.z;
        xs[xd4 * 4 + 3][tok] = v.w;
      }
      __syncthreads();
#pragma unroll 4
      for (int d = 0; d < BD; ++d) {
        const float4 a0 = *(const float4*)&xs[d][wm * 64 + tm * 8];
        const float4 a1 = *(const float4*)&xs[d][wm * 64 + tm * 8 + 4];
        const float4 b0 = *(const float4*)&es[d][wk * 64 + tk * 8];
        const float4 b1 = *(const float4*)&es[d][wk * 64 + tk * 8 + 4];
        const float av[8] = {a0.x, a0.y, a0.z, a0.w, a1.x, a1.y, a1.z, a1.w};
        const float bv[8] = {b0.x, b0.y, b0.z, b0.w, b1.x, b1.y, b1.z, b1.w};
#pragma unroll
        for (int i = 0; i < 8; ++i)
#pragma unroll
          for (int j = 0; j < 8; ++j)
            acc[i][j] = fmaf(av[i], bv[j], acc[i][j]);
      }
    }
    // fold k-tile into running best (score = dot - 0.5|e|^2)
    const int kcol = k0 + wk * 64 + tk * 8;
    float4 h0 = *(const float4*)(he2 + kcol);
    float4 h1 = *(const float4*)(he2 + kcol + 4);
    const float hv[8] = {h0.x, h0.y, h0.z, h0.w, h1.x, h1.y, h1.z, h1.w};
#pragma unroll
    for (int i = 0; i < 8; ++i) {
#pragma unroll
      for (int j = 0; j < 8; ++j) {
        float s = acc[i][j] - hv[j];
        if (s > best[i]) { best[i] = s; bidx[i] = kcol + j; }
      }
    }
  }

  // block-level reduce over the 16 k-threads per token (alias onto staging LDS)
  __syncthreads();
  float (*rv)[17] = (float (*)[17])smem;               // 128*17*4 = 8704
  int (*ri)[17] = (int (*)[17])(smem + 8704);          // 8704
#pragma unroll
  for (int i = 0; i < 8; ++i) {
    int tok = wm * 64 + tm * 8 + i;
    rv[tok][wk * 8 + tk] = best[i];
    ri[tok][wk * 8 + tk] = bidx[i];
  }
  __syncthreads();
  if (tid < BM) {
    float bv = rv[tid][0];
    int bi = ri[tid][0];
#pragma unroll
    for (int t = 1; t < 16; ++t) {
      float v = rv[tid][t];
      int ii = ri[tid][t];
      if (v > bv || (v == bv && ii < bi)) { bv = v; bi = ii; }
    }
    uint32_t b = __float_as_uint(bv);
    uint32_t m = (b & 0x80000000u) ? ~b : (b | 0x80000000u);
    unsigned long long packed =
        ((unsigned long long)m << 32) | (uint32_t)(~(uint32_t)bi);
    atomicMax(&best64[block_m + tid], packed);
  }
}

// ---------------- gather quantized + sum((q-x)^2) + counts ----------------
__global__ __launch_bounds__(256) void gather_et_kernel(
    const float* __restrict__ x, const float* __restrict__ Et,
    const unsigned long long* __restrict__ best64, float* __restrict__ out,
    float* __restrict__ partials, int* __restrict__ counts) {
  __shared__ float sh[256];
  int tid = threadIdx.x;
  int gid = blockIdx.x * 256 + tid;
  int n = gid >> 7;
  int d4 = gid & 127;
  int k = (int)(~(uint32_t)best64[n]);
  float4 q = *(const float4*)(Et + (size_t)k * DD + d4 * 4);
  float4 xv = *(const float4*)(x + (size_t)n * DD + d4 * 4);
  *(float4*)(out + (size_t)n * DD + d4 * 4) = q;
  float dx0 = q.x - xv.x, dx1 = q.y - xv.y, dx2 = q.z - xv.z, dx3 = q.w - xv.w;
  sh[tid] = dx0 * dx0 + dx1 * dx1 + dx2 * dx2 + dx3 * dx3;
  if (d4 == 0) atomicAdd(&counts[k], 1);
  __syncthreads();
  for (int s = 128; s > 0; s >>= 1) {
    if (tid < s) sh[tid] += sh[tid + s];
    __syncthreads();
  }
  if (tid == 0) atomicAdd(&partials[blockIdx.x & 255], sh[0]);
}

__global__ __launch_bounds__(256) void gather_direct_kernel(
    const float* __restrict__ x, const float* __restrict__ E,
    const unsigned long long* __restrict__ best64, float* __restrict__ out,
    float* __restrict__ partials, int* __restrict__ counts) {
  __shared__ float sh[256];
  int tid = threadIdx.x;
  int gid = blockIdx.x * 256 + tid;
  int n = gid >> 7;
  int d4 = gid & 127;
  int k = (int)(~(uint32_t)best64[n]);
  float4 q;
  q.x = E[(size_t)(d4 * 4 + 0) * KK + k];
  q.y = E[(size_t)(d4 * 4 + 1) * KK + k];
  q.z = E[(size_t)(d4 * 4 + 2) * KK + k];
  q.w = E[(size_t)(d4 * 4 + 3) * KK + k];
  float4 xv = *(const float4*)(x + (size_t)n * DD + d4 * 4);
  *(float4*)(out + (size_t)n * DD + d4 * 4) = q;
  float dx0 = q.x - xv.x, dx1 = q.y - xv.y, dx2 = q.z - xv.z, dx3 = q.w - xv.w;
  sh[tid] = dx0 * dx0 + dx1 * dx1 + dx2 * dx2 + dx3 * dx3;
  if (d4 == 0) atomicAdd(&counts[k], 1);
  __syncthreads();
  for (int s = 128; s > 0; s >>= 1) {
    if (tid < s) sh[tid] += sh[tid + s];
    __syncthreads();
  }
  if (tid == 0) atomicAdd(&partials[blockIdx.x & 255], sh[0]);
}

// ---------------- loss + perplexity ----------------
__global__ __launch_bounds__(256) void finalize_kernel(
    const int* __restrict__ counts, const float* __restrict__ partials,
    float* __restrict__ out) {
  __shared__ float sh[256];
  int tid = threadIdx.x;
  float h = 0.f;
  for (int k = tid; k < KK; k += 256) {
    float p = (float)counts[k] * (1.0f / (float)NN);
    h += p * logf(p + 1e-10f);
  }
  sh[tid] = h;
  __syncthreads();
  for (int s = 128; s > 0; s >>= 1) {
    if (tid < s) sh[tid] += sh[tid + s];
    __syncthreads();
  }
  float H = sh[0];
  __syncthreads();
  sh[tid] = partials[tid];
  __syncthreads();
  for (int s = 128; s > 0; s >>= 1) {
    if (tid < s) sh[tid] += sh[tid + s];
    __syncthreads();
  }
  if (tid == 0) {
    float mse = sh[0] / (float)((size_t)NN * DD);
    out[(size_t)NN * DD] = 1.25f * mse;   // q_loss + 0.25*e_loss (equal values)
    out[(size_t)NN * DD + 1] = expf(-H);  // perplexity
  }
}

extern "C" void kernel_launch(void* const* d_in, const int* in_sizes, int n_in,
                              void* d_out, int out_size, void* d_ws, size_t ws_size,
                              hipStream_t stream) {
  const float* x = (const float*)d_in[0];
  const float* E = (const float*)d_in[1];
  float* out = (float*)d_out;
  char* ws = (char*)d_ws;

  // ws layout (bytes)
  unsigned long long* best64 = (unsigned long long*)(ws + 0);  // 262144
  float* he2 = (float*)(ws + 262144);                          // 16384
  int* counts = (int*)(ws + 278528);                           // 16384
  float* partials = (float*)(ws + 294912);                     // 1024
  float* Et = (float*)(ws + 295936);                           // 8 MB (optional)
  const size_t need_et = 295936 + (size_t)DD * KK * 4;
  const bool use_et = ws_size >= need_et;

  // zero best64 + counts + partials (he2 region overwritten by he2_kernel)
  hipMemsetAsync(ws, 0, 295936, stream);

  he2_kernel<<<KK / 256, 256, 0, stream>>>(E, he2);
  if (use_et) transpose_kernel<<<(KK / 32) * (DD / 32), 256, 0, stream>>>(E, Et);
  argmax_kernel<<<(NN / BM) * KS, 256, 0, stream>>>(x, E, he2, best64);
  if (use_et)
    gather_et_kernel<<<(NN * (DD / 4)) / 256, 256, 0, stream>>>(x, Et, best64, out,
                                                                partials, counts);
  else
    gather_direct_kernel<<<(NN * (DD / 4)) / 256, 256, 0, stream>>>(x, E, best64, out,
                                                                    partials, counts);
  finalize_kernel<<<1, 256, 0, stream>>>(counts, partials, out);
}

// Round 3
// 657.495 us; speedup vs baseline: 3.1726x; 3.0500x over previous
//
#include <hip/hip_runtime.h>
#include <stdint.h>

#define DD 512
#define KK 4096
#define NN 32768

typedef __attribute__((ext_vector_type(8))) short bf16x8;
typedef __attribute__((ext_vector_type(4))) float f32x4;

__device__ __forceinline__ unsigned short bf16_rn(float f) {
  uint32_t u = __float_as_uint(f);
  return (unsigned short)((u + 0x7FFFu + ((u >> 16) & 1u)) >> 16);
}
__device__ __forceinline__ float bf16_tof(unsigned short h) {
  return __uint_as_float(((uint32_t)h) << 16);
}

// ---------------- 0.5*|e_k|^2 (exact fp32) ----------------
__global__ __launch_bounds__(256) void he2_kernel(const float* __restrict__ E,
                                                  float* __restrict__ he2) {
  int k = blockIdx.x * 256 + threadIdx.x;
  float s = 0.f;
#pragma unroll 8
  for (int d = 0; d < DD; ++d) {
    float v = E[(size_t)d * KK + k];
    s = fmaf(v, v, s);
  }
  he2[k] = 0.5f * s;
}

// ---------------- x -> xh/xl bf16 split ----------------
__global__ __launch_bounds__(256) void conv_x_kernel(const float4* __restrict__ x4,
                                                     unsigned short* __restrict__ xh,
                                                     unsigned short* __restrict__ xl) {
  int gid = blockIdx.x * 256 + threadIdx.x;  // N*D/4 threads
  float4 v = x4[gid];
  float vv[4] = {v.x, v.y, v.z, v.w};
  union { unsigned short u[4]; uint64_t q; } H, L;
#pragma unroll
  for (int i = 0; i < 4; ++i) {
    H.u[i] = bf16_rn(vv[i]);
    L.u[i] = bf16_rn(vv[i] - bf16_tof(H.u[i]));
  }
  *(uint64_t*)(xh + (size_t)gid * 4) = H.q;
  *(uint64_t*)(xl + (size_t)gid * 4) = L.q;
}

// ---------------- E[D,K] -> Eth/Etl[K,D] bf16 split (transposed) ----------------
__global__ __launch_bounds__(256) void conv_et_kernel(const float* __restrict__ E,
                                                      unsigned short* __restrict__ Eth,
                                                      unsigned short* __restrict__ Etl) {
  __shared__ float t[32][33];
  int bk = (blockIdx.x & 127) * 32;
  int bd = (blockIdx.x >> 7) * 32;
  int c = threadIdx.x & 31;
  int r0 = threadIdx.x >> 5;
#pragma unroll
  for (int r = r0; r < 32; r += 8) t[r][c] = E[(size_t)(bd + r) * KK + bk + c];
  __syncthreads();
#pragma unroll
  for (int r = r0; r < 32; r += 8) {
    float v = t[c][r];
    unsigned short h = bf16_rn(v);
    unsigned short l = bf16_rn(v - bf16_tof(h));
    Eth[(size_t)(bk + r) * DD + bd + c] = h;
    Etl[(size_t)(bk + r) * DD + bd + c] = l;
  }
}

// ---------------- fp32 transpose E -> Et[K,D] (for coalesced gather) ----------------
__global__ __launch_bounds__(256) void transpose_kernel(const float* __restrict__ E,
                                                        float* __restrict__ Et) {
  __shared__ float t[32][33];
  int bk = (blockIdx.x & 127) * 32;
  int bd = (blockIdx.x >> 7) * 32;
  int c = threadIdx.x & 31;
  int r0 = threadIdx.x >> 5;
#pragma unroll
  for (int r = r0; r < 32; r += 8) t[r][c] = E[(size_t)(bd + r) * KK + bk + c];
  __syncthreads();
#pragma unroll
  for (int r = r0; r < 32; r += 8) Et[(size_t)(bk + r) * DD + bd + c] = t[c][r];
}

// ---------------- MFMA scores + argmax ----------------
// grid: (NN/128) * 8 blocks; block = 128 tokens x 512 codes; K_eff = 1536
// (seg0: xh*Eth, seg1: xh*Etl, seg2: xl*Eth). 4 waves (2m x 2k), wave = 64x64
// as 4x4 MFMA 16x16x32 tiles. LDS tiles [2 halves][128 rows][32 bf16].
#define ANB 512

__global__ __launch_bounds__(256, 2) void argmax_mfma_kernel(
    const unsigned short* __restrict__ xh, const unsigned short* __restrict__ xl,
    const unsigned short* __restrict__ Eth, const unsigned short* __restrict__ Etl,
    const float* __restrict__ he2, unsigned long long* __restrict__ best64) {
  __shared__ __align__(16) char smem[32768];
  char* As = smem;           // [2][128][32] bf16 (half-stride 8192 B)
  char* Bs = smem + 16384;

  const int tid = threadIdx.x;
  const int w = tid >> 6;
  const int lane = tid & 63;
  const int wm = w >> 1, wk = w & 1;
  const int l15 = lane & 15, quad = lane >> 4;
  const int block_m = (blockIdx.x >> 3) * 128;
  const int nbase = (blockIdx.x & 7) * ANB;

  const int srow = lane >> 2;        // 0..15: staging row within 16-row group
  const int scol8 = (lane & 3) * 8;  // ushort offset within 32-col half

  float best[16];
  int bidx[16];
#pragma unroll
  for (int s = 0; s < 16; ++s) { best[s] = -INFINITY; bidx[s] = 0; }

  for (int nt = 0; nt < ANB / 128; ++nt) {
    const int ncode = nbase + nt * 128;
    f32x4 acc[4][4];
#pragma unroll
    for (int ti = 0; ti < 4; ++ti)
#pragma unroll
      for (int tj = 0; tj < 4; ++tj) acc[ti][tj] = (f32x4){0.f, 0.f, 0.f, 0.f};

    for (int seg = 0; seg < 3; ++seg) {
      const unsigned short* Ap = (seg == 2) ? xl : xh;
      const unsigned short* Bp = (seg == 1) ? Etl : Eth;
      for (int dt = 0; dt < DD; dt += 64) {
        __syncthreads();  // prior compute done before overwrite
#pragma unroll
        for (int r = 0; r < 4; ++r) {
          const int half = r & 1;
          const int rowbase = w * 32 + (r >> 1) * 16;
          const int d = dt + half * 32 + scol8;
          const unsigned short* ga = Ap + (size_t)(block_m + rowbase + srow) * DD + d;
          __builtin_amdgcn_global_load_lds(
              (const __attribute__((address_space(1))) void*)ga,
              (__attribute__((address_space(3))) void*)(As + half * 8192 + rowbase * 64),
              16, 0, 0);
          const unsigned short* gb = Bp + (size_t)(ncode + rowbase + srow) * DD + d;
          __builtin_amdgcn_global_load_lds(
              (const __attribute__((address_space(1))) void*)gb,
              (__attribute__((address_space(3))) void*)(Bs + half * 8192 + rowbase * 64),
              16, 0, 0);
        }
        __syncthreads();
#pragma unroll
        for (int s = 0; s < 2; ++s) {
          bf16x8 af[4], bfv[4];
#pragma unroll
          for (int ti = 0; ti < 4; ++ti)
            af[ti] = *(const bf16x8*)(As + s * 8192 + (wm * 64 + ti * 16 + l15) * 64 + quad * 16);
#pragma unroll
          for (int tj = 0; tj < 4; ++tj)
            bfv[tj] = *(const bf16x8*)(Bs + s * 8192 + (wk * 64 + tj * 16 + l15) * 64 + quad * 16);
#pragma unroll
          for (int ti = 0; ti < 4; ++ti)
#pragma unroll
            for (int tj = 0; tj < 4; ++tj)
              acc[ti][tj] = __builtin_amdgcn_mfma_f32_16x16x32_bf16(af[ti], bfv[tj],
                                                                    acc[ti][tj], 0, 0, 0);
        }
      }
    }
    // fold this 128-code tile: score = dot - 0.5|e|^2
    const int colb = ncode + wk * 64 + l15;
#pragma unroll
    for (int tj = 0; tj < 4; ++tj) {
      float h = he2[colb + tj * 16];
#pragma unroll
      for (int ti = 0; ti < 4; ++ti)
#pragma unroll
        for (int r = 0; r < 4; ++r) {
          float sc = acc[ti][tj][r] - h;
          int slot = ti * 4 + r;
          if (sc > best[slot]) { best[slot] = sc; bidx[slot] = colb + tj * 16; }
        }
    }
  }

  // reduce over the 16 col-lanes per row group, then cross-block atomicMax
#pragma unroll
  for (int slot = 0; slot < 16; ++slot) {
    float v = best[slot];
    int ii = bidx[slot];
#pragma unroll
    for (int m = 1; m < 16; m <<= 1) {
      float ov = __shfl_xor(v, m, 64);
      int oi = __shfl_xor(ii, m, 64);
      if (ov > v || (ov == v && oi < ii)) { v = ov; ii = oi; }
    }
    if (l15 == 0) {
      int row = block_m + wm * 64 + (slot >> 2) * 16 + quad * 4 + (slot & 3);
      uint32_t b = __float_as_uint(v);
      uint32_t mm = (b & 0x80000000u) ? ~b : (b | 0x80000000u);
      unsigned long long packed = ((unsigned long long)mm << 32) | (uint32_t)(~(uint32_t)ii);
      atomicMax(&best64[row], packed);
    }
  }
}

// ---------------- fallback fp32 argmax (R2, used when ws too small) ----------------
#define BM 128
#define BK 128
#define KS 4
#define KPB (KK / KS)
#define BD 32

__global__ __launch_bounds__(256, 4) void argmax_kernel(
    const float* __restrict__ x, const float* __restrict__ E,
    const float* __restrict__ he2, unsigned long long* __restrict__ best64) {
  __shared__ __align__(16) char smem[33280];
  float (*xs)[132] = (float (*)[132])smem;
  float (*es)[BK] = (float (*)[BK])(smem + 16896);

  const int tid = threadIdx.x;
  const int wave = tid >> 6;
  const int lane = tid & 63;
  const int wm = wave >> 1, wk = wave & 1;
  const int tm = lane >> 3, tk = lane & 7;
  const int block_m = (blockIdx.x >> 2) * BM;
  const int kbase = (blockIdx.x & 3) * KPB;

  float best[8];
  int bidx[8];
#pragma unroll
  for (int i = 0; i < 8; ++i) { best[i] = -INFINITY; bidx[i] = 0; }

  const int xtok = tid >> 3;
  const int xd4 = tid & 7;
  const int erow_lane = (lane >> 5);
  const int ecol = (lane & 31) * 4;

  for (int kt = 0; kt < KPB; kt += BK) {
    const int k0 = kbase + kt;
    float acc[8][8];
#pragma unroll
    for (int i = 0; i < 8; ++i)
#pragma unroll
      for (int j = 0; j < 8; ++j) acc[i][j] = 0.f;

    for (int dt = 0; dt < DD; dt += BD) {
      __syncthreads();
#pragma unroll
      for (int r = 0; r < 4; ++r) {
        int row = r * 8 + wave * 2;
        const float* gp = E + (size_t)(dt + row + erow_lane) * KK + k0 + ecol;
        __builtin_amdgcn_global_load_lds(
            (const __attribute__((address_space(1))) void*)gp,
            (__attribute__((address_space(3))) void*)&es[row][0], 16, 0, 0);
      }
#pragma unroll
      for (int r = 0; r < 4; ++r) {
        int tok = xtok + r * 32;
        float4 v = *(const float4*)(x + (size_t)(block_m + tok) * DD + dt + xd4 * 4);
        xs[xd4 * 4 + 0][tok] = v.x;
        xs[xd4 * 4 + 1][tok] = v.y;
        xs[xd4 * 4 + 2][tok] = v.z;
        xs[xd4 * 4 + 3][tok] = v.w;
      }
      __syncthreads();
#pragma unroll 4
      for (int d = 0; d < BD; ++d) {
        const float4 a0 = *(const float4*)&xs[d][wm * 64 + tm * 8];
        const float4 a1 = *(const float4*)&xs[d][wm * 64 + tm * 8 + 4];
        const float4 b0 = *(const float4*)&es[d][wk * 64 + tk * 8];
        const float4 b1 = *(const float4*)&es[d][wk * 64 + tk * 8 + 4];
        const float av[8] = {a0.x, a0.y, a0.z, a0.w, a1.x, a1.y, a1.z, a1.w};
        const float bv[8] = {b0.x, b0.y, b0.z, b0.w, b1.x, b1.y, b1.z, b1.w};
#pragma unroll
        for (int i = 0; i < 8; ++i)
#pragma unroll
          for (int j = 0; j < 8; ++j) acc[i][j] = fmaf(av[i], bv[j], acc[i][j]);
      }
    }
    const int kcol = k0 + wk * 64 + tk * 8;
    float4 h0 = *(const float4*)(he2 + kcol);
    float4 h1 = *(const float4*)(he2 + kcol + 4);
    const float hv[8] = {h0.x, h0.y, h0.z, h0.w, h1.x, h1.y, h1.z, h1.w};
#pragma unroll
    for (int i = 0; i < 8; ++i) {
#pragma unroll
      for (int j = 0; j < 8; ++j) {
        float s = acc[i][j] - hv[j];
        if (s > best[i]) { best[i] = s; bidx[i] = kcol + j; }
      }
    }
  }

  __syncthreads();
  float (*rv)[17] = (float (*)[17])smem;
  int (*ri)[17] = (int (*)[17])(smem + 8704);
#pragma unroll
  for (int i = 0; i < 8; ++i) {
    int tok = wm * 64 + tm * 8 + i;
    rv[tok][wk * 8 + tk] = best[i];
    ri[tok][wk * 8 + tk] = bidx[i];
  }
  __syncthreads();
  if (tid < BM) {
    float bv = rv[tid][0];
    int bi = ri[tid][0];
#pragma unroll
    for (int t = 1; t < 16; ++t) {
      float v = rv[tid][t];
      int ii = ri[tid][t];
      if (v > bv || (v == bv && ii < bi)) { bv = v; bi = ii; }
    }
    uint32_t b = __float_as_uint(bv);
    uint32_t m = (b & 0x80000000u) ? ~b : (b | 0x80000000u);
    unsigned long long packed = ((unsigned long long)m << 32) | (uint32_t)(~(uint32_t)bi);
    atomicMax(&best64[block_m + tid], packed);
  }
}

// ---------------- gather quantized + sum((q-x)^2) + counts ----------------
__global__ __launch_bounds__(256) void gather_et_kernel(
    const float* __restrict__ x, const float* __restrict__ Et,
    const unsigned long long* __restrict__ best64, float* __restrict__ out,
    float* __restrict__ partials, int* __restrict__ counts) {
  __shared__ float sh[256];
  int tid = threadIdx.x;
  int gid = blockIdx.x * 256 + tid;
  int n = gid >> 7;
  int d4 = gid & 127;
  int k = (int)(~(uint32_t)best64[n]);
  float4 q = *(const float4*)(Et + (size_t)k * DD + d4 * 4);
  float4 xv = *(const float4*)(x + (size_t)n * DD + d4 * 4);
  *(float4*)(out + (size_t)n * DD + d4 * 4) = q;
  float dx0 = q.x - xv.x, dx1 = q.y - xv.y, dx2 = q.z - xv.z, dx3 = q.w - xv.w;
  sh[tid] = dx0 * dx0 + dx1 * dx1 + dx2 * dx2 + dx3 * dx3;
  if (d4 == 0) atomicAdd(&counts[k], 1);
  __syncthreads();
  for (int s = 128; s > 0; s >>= 1) {
    if (tid < s) sh[tid] += sh[tid + s];
    __syncthreads();
  }
  if (tid == 0) atomicAdd(&partials[blockIdx.x & 255], sh[0]);
}

__global__ __launch_bounds__(256) void gather_direct_kernel(
    const float* __restrict__ x, const float* __restrict__ E,
    const unsigned long long* __restrict__ best64, float* __restrict__ out,
    float* __restrict__ partials, int* __restrict__ counts) {
  __shared__ float sh[256];
  int tid = threadIdx.x;
  int gid = blockIdx.x * 256 + tid;
  int n = gid >> 7;
  int d4 = gid & 127;
  int k = (int)(~(uint32_t)best64[n]);
  float4 q;
  q.x = E[(size_t)(d4 * 4 + 0) * KK + k];
  q.y = E[(size_t)(d4 * 4 + 1) * KK + k];
  q.z = E[(size_t)(d4 * 4 + 2) * KK + k];
  q.w = E[(size_t)(d4 * 4 + 3) * KK + k];
  float4 xv = *(const float4*)(x + (size_t)n * DD + d4 * 4);
  *(float4*)(out + (size_t)n * DD + d4 * 4) = q;
  float dx0 = q.x - xv.x, dx1 = q.y - xv.y, dx2 = q.z - xv.z, dx3 = q.w - xv.w;
  sh[tid] = dx0 * dx0 + dx1 * dx1 + dx2 * dx2 + dx3 * dx3;
  if (d4 == 0) atomicAdd(&counts[k], 1);
  __syncthreads();
  for (int s = 128; s > 0; s >>= 1) {
    if (tid < s) sh[tid] += sh[tid + s];
    __syncthreads();
  }
  if (tid == 0) atomicAdd(&partials[blockIdx.x & 255], sh[0]);
}

// ---------------- loss + perplexity ----------------
__global__ __launch_bounds__(256) void finalize_kernel(
    const int* __restrict__ counts, const float* __restrict__ partials,
    float* __restrict__ out) {
  __shared__ float sh[256];
  int tid = threadIdx.x;
  float h = 0.f;
  for (int k = tid; k < KK; k += 256) {
    float p = (float)counts[k] * (1.0f / (float)NN);
    h += p * logf(p + 1e-10f);
  }
  sh[tid] = h;
  __syncthreads();
  for (int s = 128; s > 0; s >>= 1) {
    if (tid < s) sh[tid] += sh[tid + s];
    __syncthreads();
  }
  float H = sh[0];
  __syncthreads();
  sh[tid] = partials[tid];
  __syncthreads();
  for (int s = 128; s > 0; s >>= 1) {
    if (tid < s) sh[tid] += sh[tid + s];
    __syncthreads();
  }
  if (tid == 0) {
    float mse = sh[0] / (float)((size_t)NN * DD);
    out[(size_t)NN * DD] = 1.25f * mse;
    out[(size_t)NN * DD + 1] = expf(-H);
  }
}

extern "C" void kernel_launch(void* const* d_in, const int* in_sizes, int n_in,
                              void* d_out, int out_size, void* d_ws, size_t ws_size,
                              hipStream_t stream) {
  const float* x = (const float*)d_in[0];
  const float* E = (const float*)d_in[1];
  float* out = (float*)d_out;
  char* ws = (char*)d_ws;

  // common ws layout
  unsigned long long* best64 = (unsigned long long*)(ws + 0);  // 262144
  float* he2 = (float*)(ws + 262144);                          // 16384
  int* counts = (int*)(ws + 278528);                           // 16384
  float* partials = (float*)(ws + 294912);                     // 1024
  // MFMA path extras
  unsigned short* Eth = (unsigned short*)(ws + 295936);        // 4 MiB
  unsigned short* Etl = (unsigned short*)(ws + 4490240);       // 4 MiB
  float* Et = (float*)(ws + 8684544);                          // 8 MiB (optional)
  const size_t NEED_MFMA = 8684544;
  const size_t NEED_ET = 8684544 + (size_t)DD * KK * 4;

  hipMemsetAsync(ws, 0, 295936, stream);
  he2_kernel<<<KK / 256, 256, 0, stream>>>(E, he2);

  if (ws_size >= NEED_MFMA) {
    // xh/xl live in d_out (overwritten by gather at the end)
    unsigned short* xh = (unsigned short*)d_out;
    unsigned short* xl = xh + (size_t)NN * DD;
    const bool use_et = ws_size >= NEED_ET;

    conv_x_kernel<<<(NN * DD / 4) / 256, 256, 0, stream>>>((const float4*)x, xh, xl);
    conv_et_kernel<<<(KK / 32) * (DD / 32), 256, 0, stream>>>(E, Eth, Etl);
    if (use_et) transpose_kernel<<<(KK / 32) * (DD / 32), 256, 0, stream>>>(E, Et);
    argmax_mfma_kernel<<<(NN / 128) * 8, 256, 0, stream>>>(xh, xl, Eth, Etl, he2, best64);
    if (use_et)
      gather_et_kernel<<<(NN * (DD / 4)) / 256, 256, 0, stream>>>(x, Et, best64, out,
                                                                  partials, counts);
    else
      gather_direct_kernel<<<(NN * (DD / 4)) / 256, 256, 0, stream>>>(x, E, best64, out,
                                                                      partials, counts);
  } else {
    // fp32 fallback (R2 path)
    const bool use_et = ws_size >= 295936 + (size_t)DD * KK * 4;
    float* Etf = (float*)(ws + 295936);
    if (use_et) transpose_kernel<<<(KK / 32) * (DD / 32), 256, 0, stream>>>(E, Etf);
    argmax_kernel<<<(NN / BM) * KS, 256, 0, stream>>>(x, E, he2, best64);
    if (use_et)
      gather_et_kernel<<<(NN * (DD / 4)) / 256, 256, 0, stream>>>(x, Etf, best64, out,
                                                                  partials, counts);
    else
      gather_direct_kernel<<<(NN * (DD / 4)) / 256, 256, 0, stream>>>(x, E, best64, out,
                                                                      partials, counts);
  }
  finalize_kernel<<<1, 256, 0, stream>>>(counts, partials, out);
}

// Round 4
// 597.911 us; speedup vs baseline: 3.4887x; 1.0997x over previous
//
#include <hip/hip_runtime.h>
#include <stdint.h>

#define DD 512
#define KK 4096
#define NN 32768

typedef __attribute__((ext_vector_type(8))) short bf16x8;
typedef __attribute__((ext_vector_type(4))) float f32x4;

__device__ __forceinline__ unsigned short bf16_rn(float f) {
  uint32_t u = __float_as_uint(f);
  return (unsigned short)((u + 0x7FFFu + ((u >> 16) & 1u)) >> 16);
}
__device__ __forceinline__ float bf16_tof(unsigned short h) {
  return __uint_as_float(((uint32_t)h) << 16);
}

// ---------------- 0.5*|e_k|^2 (exact fp32) ----------------
__global__ __launch_bounds__(256) void he2_kernel(const float* __restrict__ E,
                                                  float* __restrict__ he2) {
  int k = blockIdx.x * 256 + threadIdx.x;
  float s = 0.f;
#pragma unroll 8
  for (int d = 0; d < DD; ++d) {
    float v = E[(size_t)d * KK + k];
    s = fmaf(v, v, s);
  }
  he2[k] = 0.5f * s;
}

// ---------------- x -> xh/xl bf16 split ----------------
__global__ __launch_bounds__(256) void conv_x_kernel(const float4* __restrict__ x4,
                                                     unsigned short* __restrict__ xh,
                                                     unsigned short* __restrict__ xl) {
  int gid = blockIdx.x * 256 + threadIdx.x;
  float4 v = x4[gid];
  float vv[4] = {v.x, v.y, v.z, v.w};
  union { unsigned short u[4]; uint64_t q; } H, L;
#pragma unroll
  for (int i = 0; i < 4; ++i) {
    H.u[i] = bf16_rn(vv[i]);
    L.u[i] = bf16_rn(vv[i] - bf16_tof(H.u[i]));
  }
  *(uint64_t*)(xh + (size_t)gid * 4) = H.q;
  *(uint64_t*)(xl + (size_t)gid * 4) = L.q;
}

// ------- fused E prep: transpose + bf16 hi/lo split (+ optional fp32 Et) -------
template <bool WRITE_ET>
__global__ __launch_bounds__(256) void prep_et_kernel(const float* __restrict__ E,
                                                      unsigned short* __restrict__ Eth,
                                                      unsigned short* __restrict__ Etl,
                                                      float* __restrict__ Et) {
  __shared__ float t[32][33];
  int bk = (blockIdx.x & 127) * 32;
  int bd = (blockIdx.x >> 7) * 32;
  int c = threadIdx.x & 31;
  int r0 = threadIdx.x >> 5;
#pragma unroll
  for (int r = r0; r < 32; r += 8) t[r][c] = E[(size_t)(bd + r) * KK + bk + c];
  __syncthreads();
#pragma unroll
  for (int r = r0; r < 32; r += 8) {
    float v = t[c][r];
    unsigned short h = bf16_rn(v);
    unsigned short l = bf16_rn(v - bf16_tof(h));
    size_t o = (size_t)(bk + r) * DD + bd + c;
    Eth[o] = h;
    Etl[o] = l;
    if (WRITE_ET) Et[o] = v;
  }
}

// ---------------- MFMA scores + argmax ----------------
// grid: (NN/128) * 8; block = 128 tokens x 512 codes (4 nt tiles of 128).
// Per dt=32 slice: stage xh/xl/Eth/Etl tiles (4 x [128][32] bf16 = 32 KB) once,
// then 48 MFMA (xh*Eth + xh*Etl + xl*Eth) into shared accumulators.
#define ANB 512
#define BN 128

__global__ __launch_bounds__(256, 2) void argmax_mfma_kernel(
    const unsigned short* __restrict__ xh, const unsigned short* __restrict__ xl,
    const unsigned short* __restrict__ Eth, const unsigned short* __restrict__ Etl,
    const float* __restrict__ he2, unsigned long long* __restrict__ best64) {
  __shared__ __align__(16) char smem[32768];
  char* Ah = smem;            // [128][32] bf16, row stride 64 B
  char* Al = smem + 8192;
  char* Bh = smem + 16384;
  char* Bl = smem + 24576;

  const int tid = threadIdx.x;
  const int w = tid >> 6;
  const int lane = tid & 63;
  const int wm = w >> 1, wk = w & 1;
  const int l15 = lane & 15, quad = lane >> 4;
  const int block_m = (blockIdx.x >> 3) * BN;
  const int nbase = (blockIdx.x & 7) * ANB;

  const int srow = lane >> 2;        // 0..15 within a 16-row staging group
  const int scol8 = (lane & 3) * 8;  // ushort offset within 32-col row

  float best[16];
  int bidx[16];
#pragma unroll
  for (int s = 0; s < 16; ++s) { best[s] = -INFINITY; bidx[s] = 0; }

  for (int nt = 0; nt < ANB / BN; ++nt) {
    const int ncode = nbase + nt * BN;
    f32x4 acc[4][4];
#pragma unroll
    for (int ti = 0; ti < 4; ++ti)
#pragma unroll
      for (int tj = 0; tj < 4; ++tj) acc[ti][tj] = (f32x4){0.f, 0.f, 0.f, 0.f};

    for (int dt = 0; dt < DD; dt += 32) {
      __syncthreads();  // prior compute done before overwrite
#pragma unroll
      for (int r = 0; r < 2; ++r) {
        const int rowbase = w * 32 + r * 16;
        const int arow = block_m + rowbase + srow;
        const int brow = ncode + rowbase + srow;
        const int d = dt + scol8;
        __builtin_amdgcn_global_load_lds(
            (const __attribute__((address_space(1))) void*)(xh + (size_t)arow * DD + d),
            (__attribute__((address_space(3))) void*)(Ah + rowbase * 64), 16, 0, 0);
        __builtin_amdgcn_global_load_lds(
            (const __attribute__((address_space(1))) void*)(xl + (size_t)arow * DD + d),
            (__attribute__((address_space(3))) void*)(Al + rowbase * 64), 16, 0, 0);
        __builtin_amdgcn_global_load_lds(
            (const __attribute__((address_space(1))) void*)(Eth + (size_t)brow * DD + d),
            (__attribute__((address_space(3))) void*)(Bh + rowbase * 64), 16, 0, 0);
        __builtin_amdgcn_global_load_lds(
            (const __attribute__((address_space(1))) void*)(Etl + (size_t)brow * DD + d),
            (__attribute__((address_space(3))) void*)(Bl + rowbase * 64), 16, 0, 0);
      }
      __syncthreads();

      bf16x8 ah[4], bh[4];
#pragma unroll
      for (int t = 0; t < 4; ++t) {
        const int ar = (wm * 64 + t * 16 + l15) * 64 + quad * 16;
        const int br = (wk * 64 + t * 16 + l15) * 64 + quad * 16;
        ah[t] = *(const bf16x8*)(Ah + ar);
        bh[t] = *(const bf16x8*)(Bh + br);
      }
#pragma unroll
      for (int ti = 0; ti < 4; ++ti)
#pragma unroll
        for (int tj = 0; tj < 4; ++tj)
          acc[ti][tj] = __builtin_amdgcn_mfma_f32_16x16x32_bf16(ah[ti], bh[tj],
                                                                acc[ti][tj], 0, 0, 0);
      bf16x8 bl[4];
#pragma unroll
      for (int t = 0; t < 4; ++t)
        bl[t] = *(const bf16x8*)(Bl + (wk * 64 + t * 16 + l15) * 64 + quad * 16);
#pragma unroll
      for (int ti = 0; ti < 4; ++ti)
#pragma unroll
        for (int tj = 0; tj < 4; ++tj)
          acc[ti][tj] = __builtin_amdgcn_mfma_f32_16x16x32_bf16(ah[ti], bl[tj],
                                                                acc[ti][tj], 0, 0, 0);
      bf16x8 al[4];
#pragma unroll
      for (int t = 0; t < 4; ++t)
        al[t] = *(const bf16x8*)(Al + (wm * 64 + t * 16 + l15) * 64 + quad * 16);
#pragma unroll
      for (int ti = 0; ti < 4; ++ti)
#pragma unroll
        for (int tj = 0; tj < 4; ++tj)
          acc[ti][tj] = __builtin_amdgcn_mfma_f32_16x16x32_bf16(al[ti], bh[tj],
                                                                acc[ti][tj], 0, 0, 0);
    }

    // fold this 128-code tile: score = dot - 0.5|e|^2
    const int colb = ncode + wk * 64 + l15;
#pragma unroll
    for (int tj = 0; tj < 4; ++tj) {
      float h = he2[colb + tj * 16];
#pragma unroll
      for (int ti = 0; ti < 4; ++ti)
#pragma unroll
        for (int r = 0; r < 4; ++r) {
          float sc = acc[ti][tj][r] - h;
          int slot = ti * 4 + r;
          if (sc > best[slot]) { best[slot] = sc; bidx[slot] = colb + tj * 16; }
        }
    }
  }

  // reduce over the 16 col-lanes per row group, then cross-block atomicMax
#pragma unroll
  for (int slot = 0; slot < 16; ++slot) {
    float v = best[slot];
    int ii = bidx[slot];
#pragma unroll
    for (int m = 1; m < 16; m <<= 1) {
      float ov = __shfl_xor(v, m, 64);
      int oi = __shfl_xor(ii, m, 64);
      if (ov > v || (ov == v && oi < ii)) { v = ov; ii = oi; }
    }
    if (l15 == 0) {
      int row = block_m + wm * 64 + (slot >> 2) * 16 + quad * 4 + (slot & 3);
      uint32_t b = __float_as_uint(v);
      uint32_t mm = (b & 0x80000000u) ? ~b : (b | 0x80000000u);
      unsigned long long packed = ((unsigned long long)mm << 32) | (uint32_t)(~(uint32_t)ii);
      atomicMax(&best64[row], packed);
    }
  }
}

// ---------------- fallback fp32 argmax (used when ws too small) ----------------
#define BM 128
#define BK 128
#define KS 4
#define KPB (KK / KS)
#define BD 32

__global__ __launch_bounds__(256, 4) void argmax_kernel(
    const float* __restrict__ x, const float* __restrict__ E,
    const float* __restrict__ he2, unsigned long long* __restrict__ best64) {
  __shared__ __align__(16) char smem[33280];
  float (*xs)[132] = (float (*)[132])smem;
  float (*es)[BK] = (float (*)[BK])(smem + 16896);

  const int tid = threadIdx.x;
  const int wave = tid >> 6;
  const int lane = tid & 63;
  const int wm = wave >> 1, wk = wave & 1;
  const int tm = lane >> 3, tk = lane & 7;
  const int block_m = (blockIdx.x >> 2) * BM;
  const int kbase = (blockIdx.x & 3) * KPB;

  float best[8];
  int bidx[8];
#pragma unroll
  for (int i = 0; i < 8; ++i) { best[i] = -INFINITY; bidx[i] = 0; }

  const int xtok = tid >> 3;
  const int xd4 = tid & 7;
  const int erow_lane = (lane >> 5);
  const int ecol = (lane & 31) * 4;

  for (int kt = 0; kt < KPB; kt += BK) {
    const int k0 = kbase + kt;
    float acc[8][8];
#pragma unroll
    for (int i = 0; i < 8; ++i)
#pragma unroll
      for (int j = 0; j < 8; ++j) acc[i][j] = 0.f;

    for (int dt = 0; dt < DD; dt += BD) {
      __syncthreads();
#pragma unroll
      for (int r = 0; r < 4; ++r) {
        int row = r * 8 + wave * 2;
        const float* gp = E + (size_t)(dt + row + erow_lane) * KK + k0 + ecol;
        __builtin_amdgcn_global_load_lds(
            (const __attribute__((address_space(1))) void*)gp,
            (__attribute__((address_space(3))) void*)&es[row][0], 16, 0, 0);
      }
#pragma unroll
      for (int r = 0; r < 4; ++r) {
        int tok = xtok + r * 32;
        float4 v = *(const float4*)(x + (size_t)(block_m + tok) * DD + dt + xd4 * 4);
        xs[xd4 * 4 + 0][tok] = v.x;
        xs[xd4 * 4 + 1][tok] = v.y;
        xs[xd4 * 4 + 2][tok] = v.z;
        xs[xd4 * 4 + 3][tok] = v.w;
      }
      __syncthreads();
#pragma unroll 4
      for (int d = 0; d < BD; ++d) {
        const float4 a0 = *(const float4*)&xs[d][wm * 64 + tm * 8];
        const float4 a1 = *(const float4*)&xs[d][wm * 64 + tm * 8 + 4];
        const float4 b0 = *(const float4*)&es[d][wk * 64 + tk * 8];
        const float4 b1 = *(const float4*)&es[d][wk * 64 + tk * 8 + 4];
        const float av[8] = {a0.x, a0.y, a0.z, a0.w, a1.x, a1.y, a1.z, a1.w};
        const float bv[8] = {b0.x, b0.y, b0.z, b0.w, b1.x, b1.y, b1.z, b1.w};
#pragma unroll
        for (int i = 0; i < 8; ++i)
#pragma unroll
          for (int j = 0; j < 8; ++j) acc[i][j] = fmaf(av[i], bv[j], acc[i][j]);
      }
    }
    const int kcol = k0 + wk * 64 + tk * 8;
    float4 h0 = *(const float4*)(he2 + kcol);
    float4 h1 = *(const float4*)(he2 + kcol + 4);
    const float hv[8] = {h0.x, h0.y, h0.z, h0.w, h1.x, h1.y, h1.z, h1.w};
#pragma unroll
    for (int i = 0; i < 8; ++i) {
#pragma unroll
      for (int j = 0; j < 8; ++j) {
        float s = acc[i][j] - hv[j];
        if (s > best[i]) { best[i] = s; bidx[i] = kcol + j; }
      }
    }
  }

  __syncthreads();
  float (*rv)[17] = (float (*)[17])smem;
  int (*ri)[17] = (int (*)[17])(smem + 8704);
#pragma unroll
  for (int i = 0; i < 8; ++i) {
    int tok = wm * 64 + tm * 8 + i;
    rv[tok][wk * 8 + tk] = best[i];
    ri[tok][wk * 8 + tk] = bidx[i];
  }
  __syncthreads();
  if (tid < BM) {
    float bv = rv[tid][0];
    int bi = ri[tid][0];
#pragma unroll
    for (int t = 1; t < 16; ++t) {
      float v = rv[tid][t];
      int ii = ri[tid][t];
      if (v > bv || (v == bv && ii < bi)) { bv = v; bi = ii; }
    }
    uint32_t b = __float_as_uint(bv);
    uint32_t m = (b & 0x80000000u) ? ~b : (b | 0x80000000u);
    unsigned long long packed = ((unsigned long long)m << 32) | (uint32_t)(~(uint32_t)bi);
    atomicMax(&best64[block_m + tid], packed);
  }
}

// ---------------- gather quantized + sum((q-x)^2) + counts ----------------
__global__ __launch_bounds__(256) void gather_et_kernel(
    const float* __restrict__ x, const float* __restrict__ Et,
    const unsigned long long* __restrict__ best64, float* __restrict__ out,
    float* __restrict__ partials, int* __restrict__ counts) {
  __shared__ float sh[256];
  int tid = threadIdx.x;
  int gid = blockIdx.x * 256 + tid;
  int n = gid >> 7;
  int d4 = gid & 127;
  int k = (int)(~(uint32_t)best64[n]);
  float4 q = *(const float4*)(Et + (size_t)k * DD + d4 * 4);
  float4 xv = *(const float4*)(x + (size_t)n * DD + d4 * 4);
  *(float4*)(out + (size_t)n * DD + d4 * 4) = q;
  float dx0 = q.x - xv.x, dx1 = q.y - xv.y, dx2 = q.z - xv.z, dx3 = q.w - xv.w;
  sh[tid] = dx0 * dx0 + dx1 * dx1 + dx2 * dx2 + dx3 * dx3;
  if (d4 == 0) atomicAdd(&counts[k], 1);
  __syncthreads();
  for (int s = 128; s > 0; s >>= 1) {
    if (tid < s) sh[tid] += sh[tid + s];
    __syncthreads();
  }
  if (tid == 0) atomicAdd(&partials[blockIdx.x & 255], sh[0]);
}

__global__ __launch_bounds__(256) void gather_direct_kernel(
    const float* __restrict__ x, const float* __restrict__ E,
    const unsigned long long* __restrict__ best64, float* __restrict__ out,
    float* __restrict__ partials, int* __restrict__ counts) {
  __shared__ float sh[256];
  int tid = threadIdx.x;
  int gid = blockIdx.x * 256 + tid;
  int n = gid >> 7;
  int d4 = gid & 127;
  int k = (int)(~(uint32_t)best64[n]);
  float4 q;
  q.x = E[(size_t)(d4 * 4 + 0) * KK + k];
  q.y = E[(size_t)(d4 * 4 + 1) * KK + k];
  q.z = E[(size_t)(d4 * 4 + 2) * KK + k];
  q.w = E[(size_t)(d4 * 4 + 3) * KK + k];
  float4 xv = *(const float4*)(x + (size_t)n * DD + d4 * 4);
  *(float4*)(out + (size_t)n * DD + d4 * 4) = q;
  float dx0 = q.x - xv.x, dx1 = q.y - xv.y, dx2 = q.z - xv.z, dx3 = q.w - xv.w;
  sh[tid] = dx0 * dx0 + dx1 * dx1 + dx2 * dx2 + dx3 * dx3;
  if (d4 == 0) atomicAdd(&counts[k], 1);
  __syncthreads();
  for (int s = 128; s > 0; s >>= 1) {
    if (tid < s) sh[tid] += sh[tid + s];
    __syncthreads();
  }
  if (tid == 0) atomicAdd(&partials[blockIdx.x & 255], sh[0]);
}

// ---------------- loss + perplexity ----------------
__global__ __launch_bounds__(256) void finalize_kernel(
    const int* __restrict__ counts, const float* __restrict__ partials,
    float* __restrict__ out) {
  __shared__ float sh[256];
  int tid = threadIdx.x;
  float h = 0.f;
  for (int k = tid; k < KK; k += 256) {
    float p = (float)counts[k] * (1.0f / (float)NN);
    h += p * logf(p + 1e-10f);
  }
  sh[tid] = h;
  __syncthreads();
  for (int s = 128; s > 0; s >>= 1) {
    if (tid < s) sh[tid] += sh[tid + s];
    __syncthreads();
  }
  float H = sh[0];
  __syncthreads();
  sh[tid] = partials[tid];
  __syncthreads();
  for (int s = 128; s > 0; s >>= 1) {
    if (tid < s) sh[tid] += sh[tid + s];
    __syncthreads();
  }
  if (tid == 0) {
    float mse = sh[0] / (float)((size_t)NN * DD);
    out[(size_t)NN * DD] = 1.25f * mse;
    out[(size_t)NN * DD + 1] = expf(-H);
  }
}

extern "C" void kernel_launch(void* const* d_in, const int* in_sizes, int n_in,
                              void* d_out, int out_size, void* d_ws, size_t ws_size,
                              hipStream_t stream) {
  const float* x = (const float*)d_in[0];
  const float* E = (const float*)d_in[1];
  float* out = (float*)d_out;
  char* ws = (char*)d_ws;

  // common ws layout
  unsigned long long* best64 = (unsigned long long*)(ws + 0);  // 262144
  float* he2 = (float*)(ws + 262144);                          // 16384
  int* counts = (int*)(ws + 278528);                           // 16384
  float* partials = (float*)(ws + 294912);                     // 1024
  // MFMA path extras
  unsigned short* Eth = (unsigned short*)(ws + 295936);        // 4 MiB
  unsigned short* Etl = (unsigned short*)(ws + 4490240);       // 4 MiB
  float* Et = (float*)(ws + 8684544);                          // 8 MiB (optional)
  const size_t NEED_MFMA = 8684544;
  const size_t NEED_ET = 8684544 + (size_t)DD * KK * 4;

  hipMemsetAsync(ws, 0, 295936, stream);
  he2_kernel<<<KK / 256, 256, 0, stream>>>(E, he2);

  if (ws_size >= NEED_MFMA) {
    unsigned short* xh = (unsigned short*)d_out;  // overwritten by gather later
    unsigned short* xl = xh + (size_t)NN * DD;
    const bool use_et = ws_size >= NEED_ET;

    conv_x_kernel<<<(NN * DD / 4) / 256, 256, 0, stream>>>((const float4*)x, xh, xl);
    if (use_et)
      prep_et_kernel<true><<<(KK / 32) * (DD / 32), 256, 0, stream>>>(E, Eth, Etl, Et);
    else
      prep_et_kernel<false><<<(KK / 32) * (DD / 32), 256, 0, stream>>>(E, Eth, Etl, Et);
    argmax_mfma_kernel<<<(NN / 128) * 8, 256, 0, stream>>>(xh, xl, Eth, Etl, he2, best64);
    if (use_et)
      gather_et_kernel<<<(NN * (DD / 4)) / 256, 256, 0, stream>>>(x, Et, best64, out,
                                                                  partials, counts);
    else
      gather_direct_kernel<<<(NN * (DD / 4)) / 256, 256, 0, stream>>>(x, E, best64, out,
                                                                      partials, counts);
  } else {
    const bool use_et = ws_size >= 295936 + (size_t)DD * KK * 4;
    float* Etf = (float*)(ws + 295936);
    if (use_et)
      prep_et_kernel<false><<<(KK / 32) * (DD / 32), 256, 0, stream>>>(E, Eth, Etl, Etf);
    argmax_kernel<<<(NN / BM) * KS, 256, 0, stream>>>(x, E, he2, best64);
    gather_direct_kernel<<<(NN * (DD / 4)) / 256, 256, 0, stream>>>(x, E, best64, out,
                                                                    partials, counts);
  }
  finalize_kernel<<<1, 256, 0, stream>>>(counts, partials, out);
}

// Round 5
// 532.498 us; speedup vs baseline: 3.9173x; 1.1228x over previous
//
#include <hip/hip_runtime.h>
#include <stdint.h>

#define DD 512
#define KK 4096
#define NN 32768

typedef __attribute__((ext_vector_type(8))) short bf16x8;
typedef __attribute__((ext_vector_type(4))) float f32x4;

__device__ __forceinline__ unsigned short bf16_rn(float f) {
  uint32_t u = __float_as_uint(f);
  return (unsigned short)((u + 0x7FFFu + ((u >> 16) & 1u)) >> 16);
}

// ---------------- x -> bf16 cast (8 elems/thread) ----------------
__global__ __launch_bounds__(256) void conv_x_kernel(const float4* __restrict__ x4,
                                                     unsigned short* __restrict__ xh) {
  int gid = blockIdx.x * 256 + threadIdx.x;  // NN*DD/8 threads
  float4 a = x4[gid * 2];
  float4 b = x4[gid * 2 + 1];
  union { unsigned short u[8]; uint4 q; } H;
  H.u[0] = bf16_rn(a.x); H.u[1] = bf16_rn(a.y);
  H.u[2] = bf16_rn(a.z); H.u[3] = bf16_rn(a.w);
  H.u[4] = bf16_rn(b.x); H.u[5] = bf16_rn(b.y);
  H.u[6] = bf16_rn(b.z); H.u[7] = bf16_rn(b.w);
  *(uint4*)(xh + (size_t)gid * 8) = H.q;
}

// ------- fused E prep: transpose + bf16 + he2 accumulation (+ optional fp32 Et) -------
template <bool WRITE_ET>
__global__ __launch_bounds__(256) void prep_et_kernel(const float* __restrict__ E,
                                                      unsigned short* __restrict__ Eth,
                                                      float* __restrict__ he2,
                                                      float* __restrict__ Et) {
  __shared__ float t[32][33];
  int bk = (blockIdx.x & 127) * 32;
  int bd = (blockIdx.x >> 7) * 32;
  int c = threadIdx.x & 31;
  int r0 = threadIdx.x >> 5;
#pragma unroll
  for (int r = r0; r < 32; r += 8) t[r][c] = E[(size_t)(bd + r) * KK + bk + c];
  __syncthreads();
#pragma unroll
  for (int r = r0; r < 32; r += 8) {
    float v = t[c][r];  // = E[(bd+c)*KK + bk+r]  (k = bk+r, d = bd+c)
    size_t o = (size_t)(bk + r) * DD + bd + c;
    Eth[o] = bf16_rn(v);
    if (WRITE_ET) Et[o] = v;
    atomicAdd(&he2[bk + r], 0.5f * v * v);
  }
}

// ---------------- MFMA scores + argmax (single bf16 product) ----------------
// grid: (NN/128)*8; block = 128 tokens x 512 codes (4 nt tiles of 128).
// LDS: A,B tiles [128][64] bf16 (rows = 128 B), XOR-swizzled chunks:
//   LDS slot (row, pos) holds global 16B-chunk (pos ^ (row&7)).
#define ANB 512
#define BN 128

__global__ __launch_bounds__(256, 2) void argmax_mfma_kernel(
    const unsigned short* __restrict__ xh, const unsigned short* __restrict__ Eth,
    const float* __restrict__ he2, unsigned long long* __restrict__ best64) {
  __shared__ __align__(16) char smem[32768];
  char* Ah = smem;            // [128][64] bf16, row stride 128 B
  char* Bh = smem + 16384;

  const int tid = threadIdx.x;
  const int w = tid >> 6;
  const int lane = tid & 63;
  const int wm = w >> 1, wk = w & 1;
  const int l15 = lane & 15, quad = lane >> 4;
  const int block_m = (blockIdx.x >> 3) * BN;
  const int nbase = (blockIdx.x & 7) * ANB;

  const int srow = lane >> 3;                       // 0..7 row within 8-row group
  const int schunk = (lane & 7) ^ (lane >> 3);      // swizzled source chunk
  const int rx = l15 & 7;                           // frag-read xor key

  float best[16];
  int bidx[16];
#pragma unroll
  for (int s = 0; s < 16; ++s) { best[s] = -INFINITY; bidx[s] = 0; }

  for (int nt = 0; nt < ANB / BN; ++nt) {
    const int ncode = nbase + nt * BN;
    f32x4 acc[4][4];
#pragma unroll
    for (int ti = 0; ti < 4; ++ti)
#pragma unroll
      for (int tj = 0; tj < 4; ++tj) acc[ti][tj] = (f32x4){0.f, 0.f, 0.f, 0.f};

    for (int dt = 0; dt < DD; dt += 64) {
      __syncthreads();
#pragma unroll
      for (int r = 0; r < 4; ++r) {
        const int rowbase = w * 32 + r * 8;
        const int arow = block_m + rowbase + srow;
        const int brow = ncode + rowbase + srow;
        const int col = dt + schunk * 8;
        __builtin_amdgcn_global_load_lds(
            (const __attribute__((address_space(1))) void*)(xh + (size_t)arow * DD + col),
            (__attribute__((address_space(3))) void*)(Ah + rowbase * 128), 16, 0, 0);
        __builtin_amdgcn_global_load_lds(
            (const __attribute__((address_space(1))) void*)(Eth + (size_t)brow * DD + col),
            (__attribute__((address_space(3))) void*)(Bh + rowbase * 128), 16, 0, 0);
      }
      __syncthreads();
#pragma unroll
      for (int s = 0; s < 2; ++s) {
        const int ch = ((s * 4 + quad) ^ rx) * 16;
        bf16x8 af[4], bfv[4];
#pragma unroll
        for (int t = 0; t < 4; ++t) {
          af[t] = *(const bf16x8*)(Ah + (wm * 64 + t * 16 + l15) * 128 + ch);
          bfv[t] = *(const bf16x8*)(Bh + (wk * 64 + t * 16 + l15) * 128 + ch);
        }
#pragma unroll
        for (int ti = 0; ti < 4; ++ti)
#pragma unroll
          for (int tj = 0; tj < 4; ++tj)
            acc[ti][tj] = __builtin_amdgcn_mfma_f32_16x16x32_bf16(af[ti], bfv[tj],
                                                                  acc[ti][tj], 0, 0, 0);
      }
    }

    // fold this 128-code tile: score = dot - 0.5|e|^2
    const int colb = ncode + wk * 64 + l15;
#pragma unroll
    for (int tj = 0; tj < 4; ++tj) {
      float h = he2[colb + tj * 16];
#pragma unroll
      for (int ti = 0; ti < 4; ++ti)
#pragma unroll
        for (int r = 0; r < 4; ++r) {
          float sc = acc[ti][tj][r] - h;
          int slot = ti * 4 + r;
          if (sc > best[slot]) { best[slot] = sc; bidx[slot] = colb + tj * 16; }
        }
    }
  }

  // reduce over the 16 col-lanes per row group, then cross-block atomicMax
#pragma unroll
  for (int slot = 0; slot < 16; ++slot) {
    float v = best[slot];
    int ii = bidx[slot];
#pragma unroll
    for (int m = 1; m < 16; m <<= 1) {
      float ov = __shfl_xor(v, m, 64);
      int oi = __shfl_xor(ii, m, 64);
      if (ov > v || (ov == v && oi < ii)) { v = ov; ii = oi; }
    }
    if (l15 == 0) {
      int row = block_m + wm * 64 + (slot >> 2) * 16 + quad * 4 + (slot & 3);
      uint32_t b = __float_as_uint(v);
      uint32_t mm = (b & 0x80000000u) ? ~b : (b | 0x80000000u);
      unsigned long long packed = ((unsigned long long)mm << 32) | (uint32_t)(~(uint32_t)ii);
      atomicMax(&best64[row], packed);
    }
  }
}

// ---------------- fallback fp32 argmax (used when ws too small) ----------------
#define BM 128
#define BK 128
#define KS 4
#define KPB (KK / KS)
#define BD 32

__global__ __launch_bounds__(256, 4) void argmax_kernel(
    const float* __restrict__ x, const float* __restrict__ E,
    const float* __restrict__ he2, unsigned long long* __restrict__ best64) {
  __shared__ __align__(16) char smem[33280];
  float (*xs)[132] = (float (*)[132])smem;
  float (*es)[BK] = (float (*)[BK])(smem + 16896);

  const int tid = threadIdx.x;
  const int wave = tid >> 6;
  const int lane = tid & 63;
  const int wm = wave >> 1, wk = wave & 1;
  const int tm = lane >> 3, tk = lane & 7;
  const int block_m = (blockIdx.x >> 2) * BM;
  const int kbase = (blockIdx.x & 3) * KPB;

  float best[8];
  int bidx[8];
#pragma unroll
  for (int i = 0; i < 8; ++i) { best[i] = -INFINITY; bidx[i] = 0; }

  const int xtok = tid >> 3;
  const int xd4 = tid & 7;
  const int erow_lane = (lane >> 5);
  const int ecol = (lane & 31) * 4;

  for (int kt = 0; kt < KPB; kt += BK) {
    const int k0 = kbase + kt;
    float acc[8][8];
#pragma unroll
    for (int i = 0; i < 8; ++i)
#pragma unroll
      for (int j = 0; j < 8; ++j) acc[i][j] = 0.f;

    for (int dt = 0; dt < DD; dt += BD) {
      __syncthreads();
#pragma unroll
      for (int r = 0; r < 4; ++r) {
        int row = r * 8 + wave * 2;
        const float* gp = E + (size_t)(dt + row + erow_lane) * KK + k0 + ecol;
        __builtin_amdgcn_global_load_lds(
            (const __attribute__((address_space(1))) void*)gp,
            (__attribute__((address_space(3))) void*)&es[row][0], 16, 0, 0);
      }
#pragma unroll
      for (int r = 0; r < 4; ++r) {
        int tok = xtok + r * 32;
        float4 v = *(const float4*)(x + (size_t)(block_m + tok) * DD + dt + xd4 * 4);
        xs[xd4 * 4 + 0][tok] = v.x;
        xs[xd4 * 4 + 1][tok] = v.y;
        xs[xd4 * 4 + 2][tok] = v.z;
        xs[xd4 * 4 + 3][tok] = v.w;
      }
      __syncthreads();
#pragma unroll 4
      for (int d = 0; d < BD; ++d) {
        const float4 a0 = *(const float4*)&xs[d][wm * 64 + tm * 8];
        const float4 a1 = *(const float4*)&xs[d][wm * 64 + tm * 8 + 4];
        const float4 b0 = *(const float4*)&es[d][wk * 64 + tk * 8];
        const float4 b1 = *(const float4*)&es[d][wk * 64 + tk * 8 + 4];
        const float av[8] = {a0.x, a0.y, a0.z, a0.w, a1.x, a1.y, a1.z, a1.w};
        const float bv[8] = {b0.x, b0.y, b0.z, b0.w, b1.x, b1.y, b1.z, b1.w};
#pragma unroll
        for (int i = 0; i < 8; ++i)
#pragma unroll
          for (int j = 0; j < 8; ++j) acc[i][j] = fmaf(av[i], bv[j], acc[i][j]);
      }
    }
    const int kcol = k0 + wk * 64 + tk * 8;
    float4 h0 = *(const float4*)(he2 + kcol);
    float4 h1 = *(const float4*)(he2 + kcol + 4);
    const float hv[8] = {h0.x, h0.y, h0.z, h0.w, h1.x, h1.y, h1.z, h1.w};
#pragma unroll
    for (int i = 0; i < 8; ++i) {
#pragma unroll
      for (int j = 0; j < 8; ++j) {
        float s = acc[i][j] - hv[j];
        if (s > best[i]) { best[i] = s; bidx[i] = kcol + j; }
      }
    }
  }

  __syncthreads();
  float (*rv)[17] = (float (*)[17])smem;
  int (*ri)[17] = (int (*)[17])(smem + 8704);
#pragma unroll
  for (int i = 0; i < 8; ++i) {
    int tok = wm * 64 + tm * 8 + i;
    rv[tok][wk * 8 + tk] = best[i];
    ri[tok][wk * 8 + tk] = bidx[i];
  }
  __syncthreads();
  if (tid < BM) {
    float bv = rv[tid][0];
    int bi = ri[tid][0];
#pragma unroll
    for (int t = 1; t < 16; ++t) {
      float v = rv[tid][t];
      int ii = ri[tid][t];
      if (v > bv || (v == bv && ii < bi)) { bv = v; bi = ii; }
    }
    uint32_t b = __float_as_uint(bv);
    uint32_t m = (b & 0x80000000u) ? ~b : (b | 0x80000000u);
    unsigned long long packed = ((unsigned long long)m << 32) | (uint32_t)(~(uint32_t)bi);
    atomicMax(&best64[block_m + tid], packed);
  }
}

// ---------------- gather quantized + sum((q-x)^2) + counts ----------------
__global__ __launch_bounds__(256) void gather_et_kernel(
    const float* __restrict__ x, const float* __restrict__ Et,
    const unsigned long long* __restrict__ best64, float* __restrict__ out,
    float* __restrict__ partials, int* __restrict__ counts) {
  __shared__ float sh[256];
  int tid = threadIdx.x;
  int gid = blockIdx.x * 256 + tid;
  int n = gid >> 7;
  int d4 = gid & 127;
  int k = (int)(~(uint32_t)best64[n]);
  float4 q = *(const float4*)(Et + (size_t)k * DD + d4 * 4);
  float4 xv = *(const float4*)(x + (size_t)n * DD + d4 * 4);
  *(float4*)(out + (size_t)n * DD + d4 * 4) = q;
  float dx0 = q.x - xv.x, dx1 = q.y - xv.y, dx2 = q.z - xv.z, dx3 = q.w - xv.w;
  sh[tid] = dx0 * dx0 + dx1 * dx1 + dx2 * dx2 + dx3 * dx3;
  if (d4 == 0) atomicAdd(&counts[k], 1);
  __syncthreads();
  for (int s = 128; s > 0; s >>= 1) {
    if (tid < s) sh[tid] += sh[tid + s];
    __syncthreads();
  }
  if (tid == 0) atomicAdd(&partials[blockIdx.x & 255], sh[0]);
}

__global__ __launch_bounds__(256) void gather_direct_kernel(
    const float* __restrict__ x, const float* __restrict__ E,
    const unsigned long long* __restrict__ best64, float* __restrict__ out,
    float* __restrict__ partials, int* __restrict__ counts) {
  __shared__ float sh[256];
  int tid = threadIdx.x;
  int gid = blockIdx.x * 256 + tid;
  int n = gid >> 7;
  int d4 = gid & 127;
  int k = (int)(~(uint32_t)best64[n]);
  float4 q;
  q.x = E[(size_t)(d4 * 4 + 0) * KK + k];
  q.y = E[(size_t)(d4 * 4 + 1) * KK + k];
  q.z = E[(size_t)(d4 * 4 + 2) * KK + k];
  q.w = E[(size_t)(d4 * 4 + 3) * KK + k];
  float4 xv = *(const float4*)(x + (size_t)n * DD + d4 * 4);
  *(float4*)(out + (size_t)n * DD + d4 * 4) = q;
  float dx0 = q.x - xv.x, dx1 = q.y - xv.y, dx2 = q.z - xv.z, dx3 = q.w - xv.w;
  sh[tid] = dx0 * dx0 + dx1 * dx1 + dx2 * dx2 + dx3 * dx3;
  if (d4 == 0) atomicAdd(&counts[k], 1);
  __syncthreads();
  for (int s = 128; s > 0; s >>= 1) {
    if (tid < s) sh[tid] += sh[tid + s];
    __syncthreads();
  }
  if (tid == 0) atomicAdd(&partials[blockIdx.x & 255], sh[0]);
}

// ---------------- loss + perplexity ----------------
__global__ __launch_bounds__(256) void finalize_kernel(
    const int* __restrict__ counts, const float* __restrict__ partials,
    float* __restrict__ out) {
  __shared__ float sh[256];
  int tid = threadIdx.x;
  float h = 0.f;
  for (int k = tid; k < KK; k += 256) {
    float p = (float)counts[k] * (1.0f / (float)NN);
    h += p * logf(p + 1e-10f);
  }
  sh[tid] = h;
  __syncthreads();
  for (int s = 128; s > 0; s >>= 1) {
    if (tid < s) sh[tid] += sh[tid + s];
    __syncthreads();
  }
  float H = sh[0];
  __syncthreads();
  sh[tid] = partials[tid];
  __syncthreads();
  for (int s = 128; s > 0; s >>= 1) {
    if (tid < s) sh[tid] += sh[tid + s];
    __syncthreads();
  }
  if (tid == 0) {
    float mse = sh[0] / (float)((size_t)NN * DD);
    out[(size_t)NN * DD] = 1.25f * mse;
    out[(size_t)NN * DD + 1] = expf(-H);
  }
}

extern "C" void kernel_launch(void* const* d_in, const int* in_sizes, int n_in,
                              void* d_out, int out_size, void* d_ws, size_t ws_size,
                              hipStream_t stream) {
  const float* x = (const float*)d_in[0];
  const float* E = (const float*)d_in[1];
  float* out = (float*)d_out;
  char* ws = (char*)d_ws;

  // common ws layout
  unsigned long long* best64 = (unsigned long long*)(ws + 0);  // 262144
  float* he2 = (float*)(ws + 262144);                          // 16384
  int* counts = (int*)(ws + 278528);                           // 16384
  float* partials = (float*)(ws + 294912);                     // 1024
  // MFMA path extras
  unsigned short* Eth = (unsigned short*)(ws + 295936);        // 4 MiB
  float* Et = (float*)(ws + 4490240);                          // 8 MiB (optional)
  const size_t NEED_MFMA = 4490240;
  const size_t NEED_ET = 4490240 + (size_t)DD * KK * 4;

  // zero best64 + he2 (atomically accumulated) + counts + partials
  hipMemsetAsync(ws, 0, 295936, stream);

  if (ws_size >= NEED_MFMA) {
    unsigned short* xh = (unsigned short*)d_out;  // overwritten by gather later
    const bool use_et = ws_size >= NEED_ET;

    conv_x_kernel<<<(NN * DD / 8) / 256, 256, 0, stream>>>((const float4*)x, xh);
    if (use_et)
      prep_et_kernel<true><<<(KK / 32) * (DD / 32), 256, 0, stream>>>(E, Eth, he2, Et);
    else
      prep_et_kernel<false><<<(KK / 32) * (DD / 32), 256, 0, stream>>>(E, Eth, he2, Et);
    argmax_mfma_kernel<<<(NN / 128) * 8, 256, 0, stream>>>(xh, Eth, he2, best64);
    if (use_et)
      gather_et_kernel<<<(NN * (DD / 4)) / 256, 256, 0, stream>>>(x, Et, best64, out,
                                                                  partials, counts);
    else
      gather_direct_kernel<<<(NN * (DD / 4)) / 256, 256, 0, stream>>>(x, E, best64, out,
                                                                      partials, counts);
  } else {
    // fp32 fallback: needs exact he2 first (no Eth write available? reuse prep path)
    prep_et_kernel<false><<<(KK / 32) * (DD / 32), 256, 0, stream>>>(
        E, (unsigned short*)(ws + 295936), he2, (float*)nullptr);
    argmax_kernel<<<(NN / BM) * KS, 256, 0, stream>>>(x, E, he2, best64);
    gather_direct_kernel<<<(NN * (DD / 4)) / 256, 256, 0, stream>>>(x, E, best64, out,
                                                                    partials, counts);
  }
  finalize_kernel<<<1, 256, 0, stream>>>(counts, partials, out);
}